// Round 8
// baseline (1765.136 us; speedup 1.0000x reference)
//
#include <hip/hip_runtime.h>
#include <hip/hip_bf16.h>

#define D     1024
#define PED   64
#define NHEAD 16
#define NB    2
#define NN    2048
#define NHB   32      // NB*NHEAD
#define DH    68      // (D+PED)/NHEAD
#define TT    4096    // NB*NN
#define CAP   68      // kept-entry capacity per row (64 + tie slack)

typedef __attribute__((ext_vector_type(8))) short short8v;
typedef __attribute__((ext_vector_type(4))) float f32x4;

// ---------------- LayerNorm ----------------
__global__ __launch_bounds__(256) void ln_kernel(const float* __restrict__ sink,
                                                 const float* __restrict__ gw,
                                                 const float* __restrict__ bw,
                                                 float* __restrict__ feat)
{
    int row = blockIdx.x, t = threadIdx.x;
    const float* x = sink + (size_t)row * (D + PED);
    float4 v = *(const float4*)(x + (t << 2));
    float s = v.x + v.y + v.z + v.w;
    __shared__ float red[4];
    __shared__ float mu_s, rstd_s;
    for (int o = 32; o > 0; o >>= 1) s += __shfl_down(s, o);
    if ((t & 63) == 0) red[t >> 6] = s;
    __syncthreads();
    if (t == 0) mu_s = (red[0] + red[1] + red[2] + red[3]) * (1.0f / D);
    __syncthreads();
    float mu = mu_s;
    float dx = v.x - mu, dy = v.y - mu, dz = v.z - mu, dw = v.w - mu;
    float s2 = dx*dx + dy*dy + dz*dz + dw*dw;
    for (int o = 32; o > 0; o >>= 1) s2 += __shfl_down(s2, o);
    if ((t & 63) == 0) red[t >> 6] = s2;
    __syncthreads();
    if (t == 0) rstd_s = rsqrtf((red[0] + red[1] + red[2] + red[3]) * (1.0f / D) + 1e-6f);
    __syncthreads();
    float rstd = rstd_s;
    float4 gv = *(const float4*)(gw + (t << 2));
    float4 bv = *(const float4*)(bw + (t << 2));
    float4 o4;
    o4.x = dx * rstd * gv.x + bv.x;
    o4.y = dy * rstd * gv.y + bv.y;
    o4.z = dz * rstd * gv.z + bv.z;
    o4.w = dw * rstd * gv.w + bv.w;
    *(float4*)(feat + (size_t)row * D + (t << 2)) = o4;
}

// ---------------- split fp32 -> (hi, lo) bf16, elementwise (A-side, row-major kept) ----------------
__global__ __launch_bounds__(256) void split_rows(const float* __restrict__ X,
                                                  ushort* __restrict__ XH,
                                                  ushort* __restrict__ XL, int n4)
{
    unsigned gid = blockIdx.x * 256u + threadIdx.x;
    if (gid >= (unsigned)n4) return;
    float4 v = ((const float4*)X)[gid];
    float f[4] = {v.x, v.y, v.z, v.w};
    ushort hh[4], ll[4];
    #pragma unroll
    for (int i = 0; i < 4; i++) {
        __hip_bfloat16 hb = __float2bfloat16(f[i]);
        float r = f[i] - __bfloat162float(hb);
        __hip_bfloat16 lb = __float2bfloat16(r);
        hh[i] = *(ushort*)&hb; ll[i] = *(ushort*)&lb;
    }
    ushort4 H; H.x = hh[0]; H.y = hh[1]; H.z = hh[2]; H.w = hh[3];
    ushort4 L; L.x = ll[0]; L.y = ll[1]; L.z = ll[2]; L.w = ll[3];
    ((ushort4*)XH)[gid] = H;
    ((ushort4*)XL)[gid] = L;
}

// ---------------- transpose + split: W[K=1024][N] fp32 -> T{H,L}[N][1024] bf16 ----------------
__global__ __launch_bounds__(256) void tsplit(const float* __restrict__ W, int N_,
                                              ushort* __restrict__ TH,
                                              ushort* __restrict__ TL)
{
    __shared__ float tile[64][65];
    int k0 = blockIdx.y << 6, n0 = blockIdx.x << 6;
    int tx = threadIdx.x & 63, ty4 = threadIdx.x >> 6;
    for (int r = ty4; r < 64; r += 4)
        tile[r][tx] = W[(size_t)(k0 + r) * N_ + n0 + tx];
    __syncthreads();
    for (int r = ty4; r < 64; r += 4) {
        float v = tile[tx][r];
        __hip_bfloat16 hb = __float2bfloat16(v);
        float rr = v - __bfloat162float(hb);
        __hip_bfloat16 lb = __float2bfloat16(rr);
        TH[(size_t)(n0 + r) * 1024 + k0 + tx] = *(ushort*)&hb;
        TL[(size_t)(n0 + r) * 1024 + k0 + tx] = *(ushort*)&lb;
    }
}

// ---------------- bf16x3-split MFMA GEMM: C[M][ldc] = A[M][1024] @ (BT[N][1024])^T + bias ----------------
// A given as AH/AL row-major bf16; B given pre-transposed BTH/BTL [N][1024] bf16.
// 256 threads = 4 waves; block tile 64x64; wave w -> rows [m0+16w, +16), 4 col-frags of 16.
__global__ __launch_bounds__(256) void gemm_bf3(const ushort* __restrict__ AH,
                                                const ushort* __restrict__ AL,
                                                const ushort* __restrict__ BTH,
                                                const ushort* __restrict__ BTL,
                                                const float* __restrict__ bias,
                                                float* __restrict__ C, int ldc)
{
    const int K = 1024;
    int t = threadIdx.x;
    int w = t >> 6, l = t & 63;
    int m0 = (blockIdx.y << 6) + (w << 4);
    int n0 = blockIdx.x << 6;
    int lr = l & 15, lg = l >> 4;
    f32x4 acc[4] = {{0.f,0.f,0.f,0.f},{0.f,0.f,0.f,0.f},{0.f,0.f,0.f,0.f},{0.f,0.f,0.f,0.f}};
    const ushort* aH = AH + (size_t)(m0 + lr) * K + (lg << 3);
    const ushort* aL = AL + (size_t)(m0 + lr) * K + (lg << 3);
    const ushort* bH = BTH + (size_t)(n0 + lr) * K + (lg << 3);
    const ushort* bL = BTL + (size_t)(n0 + lr) * K + (lg << 3);
    for (int k0 = 0; k0 < K; k0 += 32) {
        short8v ah = *(const short8v*)(aH + k0);
        short8v al = *(const short8v*)(aL + k0);
        #pragma unroll
        for (int n = 0; n < 4; n++) {
            short8v bh = *(const short8v*)(bH + ((size_t)(n << 4) * K) + k0);
            short8v bl = *(const short8v*)(bL + ((size_t)(n << 4) * K) + k0);
            acc[n] = __builtin_amdgcn_mfma_f32_16x16x32_bf16(ah, bh, acc[n], 0, 0, 0);
            acc[n] = __builtin_amdgcn_mfma_f32_16x16x32_bf16(ah, bl, acc[n], 0, 0, 0);
            acc[n] = __builtin_amdgcn_mfma_f32_16x16x32_bf16(al, bh, acc[n], 0, 0, 0);
        }
    }
    #pragma unroll
    for (int n = 0; n < 4; n++) {
        int col = n0 + (n << 4) + lr;
        float bv = bias[col];
        #pragma unroll
        for (int j = 0; j < 4; j++) {
            int rrow = m0 + (lg << 2) + j;
            C[(size_t)rrow * ldc + col] = acc[n][j] + bv;
        }
    }
}

// ---------------- repack into per-head q/k/v (scale folded into q; exact: 0.125 = 2^-3) ----------------
__global__ __launch_bounds__(256) void repack_kernel(const float* __restrict__ q,
                                                     const float* __restrict__ kv,
                                                     const float* __restrict__ sink,
                                                     float* __restrict__ qh,
                                                     float* __restrict__ kh,
                                                     float* __restrict__ vh)
{
    unsigned gid = blockIdx.x * 256u + threadIdx.x;
    if (gid >= (unsigned)NHB * NN * DH) return;
    int d = gid % DH;
    unsigned r2 = gid / DH;
    int i = r2 & (NN - 1);
    int hb = r2 >> 11;
    int hh = hb & (NHEAD - 1), b0 = hb >> 4;
    int row = (b0 << 11) + i;
    int c = hh * DH + d;
    float qv, kvv, vv;
    if (c < D) {
        qv  = q [(size_t)row * D + c];
        kvv = kv[(size_t)row * (2 * D) + c];
        vv  = kv[(size_t)row * (2 * D) + D + c];
    } else {
        float pe = sink[(size_t)row * (D + PED) + c];
        qv = pe; kvv = pe; vv = pe;
    }
    qh[gid] = 0.125f * qv;
    kh[gid] = kvv;
    vh[gid] = vv;
}

// ---------------- sim = Qh · Khᵀ per head (64x64 tiles) ----------------
__global__ __launch_bounds__(256) void sim_kernel(const float* __restrict__ qh,
                                                  const float* __restrict__ kh,
                                                  float* __restrict__ simBuf, int hb0)
{
    __shared__ float Qt[DH * DH];
    __shared__ float Kt[DH * DH];
    int g = blockIdx.z, hb = hb0 + g;
    int i0 = blockIdx.y << 6, j0 = blockIdx.x << 6;
    int t = threadIdx.x;
    const float* qbase = qh + ((size_t)hb * NN + i0) * DH;
    const float* kbase = kh + ((size_t)hb * NN + j0) * DH;
    for (int e = t; e < 64 * DH; e += 256) {
        int r = e / DH, d = e - r * DH;
        Qt[d * DH + r] = qbase[e];
        Kt[d * DH + r] = kbase[e];
    }
    __syncthreads();
    int tx = t & 15, ty = t >> 4;
    float acc[4][4] = {};
    #pragma unroll 4
    for (int k = 0; k < DH; k++) {
        float4 a4 = *(const float4*)&Qt[k * DH + (ty << 2)];
        float4 b4 = *(const float4*)&Kt[k * DH + (tx << 2)];
        float ar_[4] = {a4.x, a4.y, a4.z, a4.w};
        float br_[4] = {b4.x, b4.y, b4.z, b4.w};
        #pragma unroll
        for (int r = 0; r < 4; r++)
            #pragma unroll
            for (int c = 0; c < 4; c++)
                acc[r][c] = fmaf(ar_[r], br_[c], acc[r][c]);
    }
    #pragma unroll
    for (int r = 0; r < 4; r++) {
        float4 o;
        o.x = acc[r][0]; o.y = acc[r][1]; o.z = acc[r][2]; o.w = acc[r][3];
        *(float4*)(simBuf + ((size_t)g * NN + i0 + (ty << 2) + r) * NN + j0 + (tx << 2)) = o;
    }
}

// ---------------- exact top-k threshold: wave-per-row bisection ----------------
__device__ __forceinline__ unsigned fmap(float f) {
    unsigned u = __float_as_uint(f);
    return (u & 0x80000000u) ? ~u : (u | 0x80000000u);
}
__device__ __forceinline__ float funmap(unsigned u) {
    return __uint_as_float((u & 0x80000000u) ? (u & 0x7fffffffu) : ~u);
}

__device__ __forceinline__ int waveCountGE(const unsigned* u, unsigned piv) {
    int c = 0;
    #pragma unroll
    for (int j = 0; j < 32; j++) c += (u[j] >= piv) ? 1 : 0;
    #pragma unroll
    for (int o = 32; o > 0; o >>= 1) c += __shfl_down(c, o);
    return __shfl(c, 0);
}

__global__ __launch_bounds__(256) void topk_kernel(const float* __restrict__ sim, int hb0,
                                                   const int* __restrict__ topt,
                                                   int* __restrict__ keptIdx,
                                                   float* __restrict__ keptVal,
                                                   int* __restrict__ keptCnt)
{
    int rid = (blockIdx.x << 2) + (threadIdx.x >> 6);
    int lane = threadIdx.x & 63;
    int g = rid >> 11, i = rid & (NN - 1);
    int hb = hb0 + g;
    const float* row = sim + ((size_t)rid << 11);
    int k = topt[0];

    unsigned u[32];
    #pragma unroll
    for (int c = 0; c < 32; c++) u[c] = fmap(row[(c << 6) + lane]);

    unsigned lo = 0u, hi = 0xFFFFFFFFu;
    while (lo < hi) {
        unsigned mid = lo + ((hi - lo) >> 1) + 1u;
        int cnt = waveCountGE(u, mid);
        if (cnt >= k) lo = mid; else hi = mid - 1u;
    }
    unsigned kth = lo;
    int total = waveCountGE(u, kth);

    size_t base = ((size_t)hb * NN + i) * CAP;
    int pbase = 0;
    #pragma unroll
    for (int c = 0; c < 32; c++) {
        bool p = (u[c] >= kth);
        unsigned long long m = __ballot(p);
        if (p) {
            int pos = pbase + (int)__popcll(m & ((1ull << lane) - 1ull));
            if (pos < CAP) {
                keptIdx[base + pos] = (c << 6) + lane;
                keptVal[base + pos] = funmap(u[c]);
            }
        }
        pbase += (int)__popcll(m);
    }
    if (lane == 0) keptCnt[hb * NN + i] = (total < CAP) ? total : CAP;
}

// ---------------- column partition function Z_j ----------------
__global__ __launch_bounds__(256) void colz_kernel(const int* __restrict__ keptIdx,
                                                   const float* __restrict__ keptVal,
                                                   const int* __restrict__ keptCnt,
                                                   float* __restrict__ colZ)
{
    unsigned gid = blockIdx.x * 256u + threadIdx.x;
    if (gid >= (unsigned)NHB * NN * CAP) return;
    int p = gid % CAP;
    unsigned rid = gid / CAP;
    if (p < keptCnt[rid]) {
        int hb = rid >> 11;
        atomicAdd(&colZ[(hb << 11) + keptIdx[(size_t)rid * CAP + p]],
                  expf(keptVal[(size_t)rid * CAP + p]));
    }
}

// ---------------- per-head stats (parallelized: grid NHB x 8, atomic accumulate) ----------------
__global__ void stats_kernel(const float* __restrict__ colZ, const float* __restrict__ vh,
                             int* __restrict__ nE, float* __restrict__ vsumE,
                             float* __restrict__ vsumAll)
{
    int hb = blockIdx.x, jb = blockIdx.y;
    int t = threadIdx.x;   // 272 = 4*68
    int ty = t / DH, d = t - ty * DH;
    float aAll = 0.f, aE = 0.f;
    int cE = 0;
    for (int j = (jb << 8) + ty; j < (jb << 8) + 256; j += 4) {
        float z = colZ[(hb << 11) + j];
        float vv = vh[((size_t)(hb << 11) + j) * DH + d];
        aAll += vv;
        if (z == 0.0f) { aE += vv; cE++; }
    }
    __shared__ float sAll[4][DH], sE[4][DH];
    __shared__ int sC[4];
    sAll[ty][d] = aAll;
    sE[ty][d] = aE;
    if (d == 0) sC[ty] = cE;
    __syncthreads();
    if (ty == 0) {
        atomicAdd(&vsumAll[hb * DH + d], sAll[0][d] + sAll[1][d] + sAll[2][d] + sAll[3][d]);
        atomicAdd(&vsumE[hb * DH + d],   sE[0][d] + sE[1][d] + sE[2][d] + sE[3][d]);
        if (d == 0) atomicAdd(&nE[hb], sC[0] + sC[1] + sC[2] + sC[3]);
    }
}

// ---------------- sparse PV + renormalization ----------------
__global__ __launch_bounds__(128) void pv_kernel(const int* __restrict__ keptIdx,
                                                 const float* __restrict__ keptVal,
                                                 const int* __restrict__ keptCnt,
                                                 const float* __restrict__ colZ,
                                                 const float* __restrict__ vh,
                                                 const int* __restrict__ nE,
                                                 const float* __restrict__ vsumE,
                                                 const float* __restrict__ vsumAll,
                                                 float* __restrict__ outcat,
                                                 float* __restrict__ dout)
{
    int bid = blockIdx.x;
    int hb = bid >> 11, i = bid & (NN - 1);
    int t = threadIdx.x;
    __shared__ float w[CAP];
    __shared__ int jj[CAP];
    __shared__ float rowsum_s;
    int cnt = keptCnt[bid];
    size_t base = (size_t)bid * CAP;
    if (t < cnt) {
        int j = keptIdx[base + t];
        jj[t] = j;
        w[t] = expf(keptVal[base + t]) / colZ[(hb << 11) + j];
    }
    __syncthreads();
    if (t == 0) {
        float s = 0.f;
        for (int p = 0; p < cnt; p++) s += w[p];
        rowsum_s = s + (float)nE[hb] * (1.0f / NN) + (float)NN * 1e-6f;
    }
    __syncthreads();
    if (t < DH) {
        float acc = 1e-6f * vsumAll[hb * DH + t] + (1.0f / NN) * vsumE[hb * DH + t];
        const float* vbase = vh + ((size_t)(hb << 11)) * DH;
        for (int p = 0; p < cnt; p++)
            acc = fmaf(w[p], vbase[(size_t)jj[p] * DH + t], acc);
        float val = acc / rowsum_s;
        int hh = hb & (NHEAD - 1), b0 = hb >> 4;
        int row = (b0 << 11) + i;
        int c = hh * DH + t;
        if (c < D) outcat[(size_t)row * D + c] = val;
        else       dout[(size_t)row * (D + PED) + c] = val;
    }
}

// ---------------- launch ----------------
extern "C" void kernel_launch(void* const* d_in, const int* in_sizes, int n_in,
                              void* d_out, int out_size, void* d_ws, size_t ws_size,
                              hipStream_t stream)
{
    (void)in_sizes; (void)n_in; (void)out_size;
    const float* sink = (const float*)d_in[0];
    const float* gno  = (const float*)d_in[1];
    const float* bno  = (const float*)d_in[2];
    const float* Wq   = (const float*)d_in[3];
    const float* bq   = (const float*)d_in[4];
    const float* Wkv  = (const float*)d_in[5];
    const float* bkv  = (const float*)d_in[6];
    const float* Wout = (const float*)d_in[7];
    const float* bout = (const float*)d_in[8];
    const int*   topt = (const int*)d_in[9];
    float* out = (float*)d_out;

    char* ws = (char*)d_ws;
    // Region A (64 MB): feat, q, kv fp32. Dead after repack -> simBuf fallback.
    float* feat = (float*)(ws + 0);
    float* q    = (float*)(ws + (size_t)TT * D * 4);
    float* kv   = (float*)(ws + (size_t)2 * TT * D * 4);
    size_t off  = (size_t)4 * TT * D * 4;                                    // 64 MB
    float* qh      = (float*)(ws + off); off += (size_t)NHB * NN * DH * 4;
    float* kh      = (float*)(ws + off); off += (size_t)NHB * NN * DH * 4;
    float* vh      = (float*)(ws + off); off += (size_t)NHB * NN * DH * 4;
    int*   keptIdx = (int*)  (ws + off); off += (size_t)NHB * NN * CAP * 4;
    float* keptVal = (float*)(ws + off); off += (size_t)NHB * NN * CAP * 4;
    int*   keptCnt = (int*)  (ws + off); off += (size_t)NHB * NN * 4;
    float* colZ    = (float*)(ws + off); off += (size_t)NHB * NN * 4;
    char*  statsZ  = (char*)(ws + off);   // nE + vsumE + vsumAll contiguous
    int*   nE      = (int*)  (ws + off); off += 256;
    float* vsumE   = (float*)(ws + off); off += (size_t)NHB * DH * 4 + 192;
    float* vsumAll = (float*)(ws + off); off += (size_t)NHB * DH * 4 + 192;
    size_t statsBytes = (size_t)((char*)(ws + off) - statsZ);
    float* outcat  = (float*)(ws + off); off += (size_t)TT * D * 4;          // 16 MB
    // bf16 split buffers (48 MB)
    ushort* featH   = (ushort*)(ws + off); off += (size_t)TT * D * 2;
    ushort* featL   = (ushort*)(ws + off); off += (size_t)TT * D * 2;
    ushort* WqTH    = (ushort*)(ws + off); off += (size_t)D * D * 2;
    ushort* WqTL    = (ushort*)(ws + off); off += (size_t)D * D * 2;
    ushort* WkvTH   = (ushort*)(ws + off); off += (size_t)D * 2 * D * 2;
    ushort* WkvTL   = (ushort*)(ws + off); off += (size_t)D * 2 * D * 2;
    ushort* WoutTH  = (ushort*)(ws + off); off += (size_t)D * D * 2;
    ushort* WoutTL  = (ushort*)(ws + off); off += (size_t)D * D * 2;
    ushort* outcH   = (ushort*)(ws + off); off += (size_t)TT * D * 2;
    ushort* outcL   = (ushort*)(ws + off); off += (size_t)TT * D * 2;

    size_t simBytesPerHead = (size_t)NN * NN * 4;
    size_t tail = (ws_size > off) ? (ws_size - off) : 0;
    int Gtail = (int)(tail / simBytesPerHead);
    float* simBuf;
    int G;
    if (Gtail > 4) {
        simBuf = (float*)(ws + off);
        G = (Gtail < NHB) ? Gtail : NHB;
    } else {
        simBuf = (float*)ws;   // region A, free after repack
        G = 4;
    }

    ln_kernel<<<TT, 256, 0, stream>>>(sink, gno, bno, feat);
    split_rows<<<(TT * D / 4 + 255) / 256, 256, 0, stream>>>(feat, featH, featL, TT * D / 4);
    tsplit<<<dim3(D / 64, D / 64), 256, 0, stream>>>(Wq, D, WqTH, WqTL);
    tsplit<<<dim3(2 * D / 64, D / 64), 256, 0, stream>>>(Wkv, 2 * D, WkvTH, WkvTL);
    tsplit<<<dim3(D / 64, D / 64), 256, 0, stream>>>(Wout, D, WoutTH, WoutTL);
    gemm_bf3<<<dim3(D / 64, TT / 64), 256, 0, stream>>>(featH, featL, WqTH, WqTL, bq, q, D);
    gemm_bf3<<<dim3(2 * D / 64, TT / 64), 256, 0, stream>>>(featH, featL, WkvTH, WkvTL, bkv, kv, 2 * D);
    repack_kernel<<<((unsigned)NHB * NN * DH + 255) / 256, 256, 0, stream>>>(q, kv, sink, qh, kh, vh);
    hipMemsetAsync(colZ, 0, (size_t)NHB * NN * 4, stream);
    hipMemsetAsync(statsZ, 0, statsBytes, stream);

    for (int hb0 = 0; hb0 < NHB; hb0 += G) {
        int gc = (NHB - hb0 < G) ? (NHB - hb0) : G;
        sim_kernel<<<dim3(NN / 64, NN / 64, gc), 256, 0, stream>>>(qh, kh, simBuf, hb0);
        topk_kernel<<<gc * 512, 256, 0, stream>>>(simBuf, hb0, topt, keptIdx, keptVal, keptCnt);
    }

    colz_kernel<<<((unsigned)NHB * NN * CAP + 255) / 256, 256, 0, stream>>>(keptIdx, keptVal, keptCnt, colZ);
    stats_kernel<<<dim3(NHB, 8), 4 * DH, 0, stream>>>(colZ, vh, nE, vsumE, vsumAll);
    pv_kernel<<<NHB * NN, 128, 0, stream>>>(keptIdx, keptVal, keptCnt, colZ, vh, nE, vsumE, vsumAll, outcat, out);
    split_rows<<<(TT * D / 4 + 255) / 256, 256, 0, stream>>>(outcat, outcH, outcL, TT * D / 4);
    gemm_bf3<<<dim3(D / 64, TT / 64), 256, 0, stream>>>(outcH, outcL, WoutTH, WoutTL, bout, out, D + PED);
}

// Round 10
// 1346.410 us; speedup vs baseline: 1.3110x; 1.3110x over previous
//
#include <hip/hip_runtime.h>
#include <hip/hip_bf16.h>

#define D     1024
#define PED   64
#define NHEAD 16
#define NB    2
#define NN    2048
#define NHB   32      // NB*NHEAD
#define DH    68      // (D+PED)/NHEAD
#define TT    4096    // NB*NN
#define CAP   68      // kept-entry capacity per row (64 + tie slack)

typedef __attribute__((ext_vector_type(8))) short short8v;
typedef __attribute__((ext_vector_type(4))) float f32x4;

__device__ __forceinline__ void gload16(const void* g, void* l) {
    __builtin_amdgcn_global_load_lds((const __attribute__((address_space(1))) void*)g,
                                     (__attribute__((address_space(3))) void*)l, 16, 0, 0);
}

__device__ __forceinline__ void bf16split(float v, ushort& h, ushort& l) {
    __hip_bfloat16 hb = __float2bfloat16(v);
    float r = v - __bfloat162float(hb);
    __hip_bfloat16 lb = __float2bfloat16(r);
    h = *(ushort*)&hb; l = *(ushort*)&lb;
}

// ---------------- LayerNorm -> bf16 hi/lo directly ----------------
__global__ __launch_bounds__(256) void ln_kernel(const float* __restrict__ sink,
                                                 const float* __restrict__ gw,
                                                 const float* __restrict__ bw,
                                                 ushort* __restrict__ featH,
                                                 ushort* __restrict__ featL)
{
    int row = blockIdx.x, t = threadIdx.x;
    const float* x = sink + (size_t)row * (D + PED);
    float4 v = *(const float4*)(x + (t << 2));
    float s = v.x + v.y + v.z + v.w;
    __shared__ float red[4];
    __shared__ float mu_s, rstd_s;
    for (int o = 32; o > 0; o >>= 1) s += __shfl_down(s, o);
    if ((t & 63) == 0) red[t >> 6] = s;
    __syncthreads();
    if (t == 0) mu_s = (red[0] + red[1] + red[2] + red[3]) * (1.0f / D);
    __syncthreads();
    float mu = mu_s;
    float dx = v.x - mu, dy = v.y - mu, dz = v.z - mu, dw = v.w - mu;
    float s2 = dx*dx + dy*dy + dz*dz + dw*dw;
    for (int o = 32; o > 0; o >>= 1) s2 += __shfl_down(s2, o);
    if ((t & 63) == 0) red[t >> 6] = s2;
    __syncthreads();
    if (t == 0) rstd_s = rsqrtf((red[0] + red[1] + red[2] + red[3]) * (1.0f / D) + 1e-6f);
    __syncthreads();
    float rstd = rstd_s;
    float4 gv = *(const float4*)(gw + (t << 2));
    float4 bv = *(const float4*)(bw + (t << 2));
    float o4[4];
    o4[0] = dx * rstd * gv.x + bv.x;
    o4[1] = dy * rstd * gv.y + bv.y;
    o4[2] = dz * rstd * gv.z + bv.z;
    o4[3] = dw * rstd * gv.w + bv.w;
    ushort4 H, L;
    bf16split(o4[0], H.x, L.x);
    bf16split(o4[1], H.y, L.y);
    bf16split(o4[2], H.z, L.z);
    bf16split(o4[3], H.w, L.w);
    *(ushort4*)(featH + (size_t)row * D + (t << 2)) = H;
    *(ushort4*)(featL + (size_t)row * D + (t << 2)) = L;
}

// ---------------- transpose + split: W[K=1024][N_] fp32 -> T{H,L}[N_][1024] bf16 ----------------
__global__ __launch_bounds__(256) void tsplit(const float* __restrict__ W, int N_,
                                              ushort* __restrict__ TH,
                                              ushort* __restrict__ TL)
{
    __shared__ float tile[64][65];
    int k0 = blockIdx.y << 6, n0 = blockIdx.x << 6;
    int tx = threadIdx.x & 63, ty4 = threadIdx.x >> 6;
    for (int r = ty4; r < 64; r += 4)
        tile[r][tx] = W[(size_t)(k0 + r) * N_ + n0 + tx];
    __syncthreads();
    for (int r = ty4; r < 64; r += 4) {
        ushort h, l;
        bf16split(tile[tx][r], h, l);
        TH[(size_t)(n0 + r) * 1024 + k0 + tx] = h;
        TL[(size_t)(n0 + r) * 1024 + k0 + tx] = l;
    }
}

// ---------------- bf16x3-split MFMA GEMM, LDS-staged, 128x128 tile, dbuf 2-phase ----------------
// C[M][ldc] = A[M][1024] @ BT[N][1024]^T + bias; A,BT as bf16 hi/lo pairs.
__global__ __launch_bounds__(256) void gemm_mfma(const ushort* __restrict__ AHg,
                                                 const ushort* __restrict__ ALg,
                                                 const ushort* __restrict__ BHg,
                                                 const ushort* __restrict__ BLg,
                                                 const float* __restrict__ biasA,
                                                 const float* __restrict__ biasB,
                                                 int bSplit,
                                                 float* __restrict__ C, int ldc)
{
    __shared__ ushort ldsAH[2][4096];   // [buf][128 rows * 32 k]
    __shared__ ushort ldsAL[2][4096];
    __shared__ ushort ldsBH[2][4096];
    __shared__ ushort ldsBL[2][4096];

    int t = threadIdx.x;
    // XCD-bijective swizzle (grid % 8 == 0 guaranteed by launch)
    int nwg = gridDim.x * gridDim.y;
    int bid = blockIdx.y * gridDim.x + blockIdx.x;
    int qq = nwg >> 3;
    int swz = (bid & 7) * qq + (bid >> 3);
    int nb = swz % gridDim.x, mb = swz / gridDim.x;
    int m0 = mb << 7, n0 = nb << 7;

    int w = t >> 6, lane = t & 63;
    int wm = w >> 1, wn = w & 1;
    int lr = lane & 15, lg = lane >> 4;

    f32x4 acc[4][4] = {};

#define STAGE(buf, kt) do {                                                          \
    int k0_ = (kt) << 5;                                                             \
    _Pragma("unroll")                                                                \
    for (int c2 = 0; c2 < 2; c2++) {                                                 \
        int idx = t + (c2 << 8);                                                     \
        int row_ = idx >> 2, kp_ = idx & 3;                                          \
        size_t ga = (size_t)(m0 + row_) * 1024 + k0_ + (kp_ << 3);                   \
        size_t gb = (size_t)(n0 + row_) * 1024 + k0_ + (kp_ << 3);                   \
        gload16(AHg + ga, &ldsAH[buf][idx << 3]);                                    \
        gload16(ALg + ga, &ldsAL[buf][idx << 3]);                                    \
        gload16(BHg + gb, &ldsBH[buf][idx << 3]);                                    \
        gload16(BLg + gb, &ldsBL[buf][idx << 3]);                                    \
    }                                                                                \
} while (0)

    STAGE(0, 0);
    __syncthreads();
    #pragma unroll 2
    for (int kt = 0; kt < 32; kt++) {
        int cur = kt & 1;
        if (kt < 31) STAGE(cur ^ 1, kt + 1);
        short8v ah[4], al[4];
        #pragma unroll
        for (int mf = 0; mf < 4; mf++) {
            int idx = ((wm << 6) + (mf << 4) + lr) * 32 + (lg << 3);
            ah[mf] = *(const short8v*)&ldsAH[cur][idx];
            al[mf] = *(const short8v*)&ldsAL[cur][idx];
        }
        #pragma unroll
        for (int nf = 0; nf < 4; nf++) {
            int idx = ((wn << 6) + (nf << 4) + lr) * 32 + (lg << 3);
            short8v bh = *(const short8v*)&ldsBH[cur][idx];
            short8v bl = *(const short8v*)&ldsBL[cur][idx];
            #pragma unroll
            for (int mf = 0; mf < 4; mf++) {
                acc[mf][nf] = __builtin_amdgcn_mfma_f32_16x16x32_bf16(ah[mf], bh, acc[mf][nf], 0, 0, 0);
                acc[mf][nf] = __builtin_amdgcn_mfma_f32_16x16x32_bf16(ah[mf], bl, acc[mf][nf], 0, 0, 0);
                acc[mf][nf] = __builtin_amdgcn_mfma_f32_16x16x32_bf16(al[mf], bh, acc[mf][nf], 0, 0, 0);
            }
        }
        __syncthreads();
    }
#undef STAGE

    #pragma unroll
    for (int nf = 0; nf < 4; nf++) {
        int col = n0 + (wn << 6) + (nf << 4) + lr;
        float bv = (col < bSplit) ? biasA[col] : biasB[col - bSplit];
        #pragma unroll
        for (int mf = 0; mf < 4; mf++) {
            int rowb = m0 + (wm << 6) + (mf << 4) + (lg << 2);
            #pragma unroll
            for (int j = 0; j < 4; j++)
                C[(size_t)(rowb + j) * ldc + col] = acc[mf][nf][j] + bv;
        }
    }
}

// ---------------- repack qkv -> per-head q/k/v (scale 0.125 folded into q) ----------------
__global__ __launch_bounds__(256) void repack_kernel(const float* __restrict__ qkv,
                                                     const float* __restrict__ sink,
                                                     float* __restrict__ qh,
                                                     float* __restrict__ kh,
                                                     float* __restrict__ vh)
{
    unsigned gid = blockIdx.x * 256u + threadIdx.x;
    if (gid >= (unsigned)NHB * NN * DH) return;
    int d = gid % DH;
    unsigned r2 = gid / DH;
    int i = r2 & (NN - 1);
    int hb = r2 >> 11;
    int hh = hb & (NHEAD - 1), b0 = hb >> 4;
    int row = (b0 << 11) + i;
    int c = hh * DH + d;
    float qv, kvv, vv;
    if (c < D) {
        const float* base = qkv + (size_t)row * 3072;
        qv  = base[c];
        kvv = base[1024 + c];
        vv  = base[2048 + c];
    } else {
        float pe = sink[(size_t)row * (D + PED) + c];
        qv = pe; kvv = pe; vv = pe;
    }
    qh[gid] = 0.125f * qv;
    kh[gid] = kvv;
    vh[gid] = vv;
}

// ---------------- sim = Qh · Khᵀ per head (64x64 tiles) ----------------
__global__ __launch_bounds__(256) void sim_kernel(const float* __restrict__ qh,
                                                  const float* __restrict__ kh,
                                                  float* __restrict__ simBuf, int hb0)
{
    __shared__ float Qt[DH * DH];
    __shared__ float Kt[DH * DH];
    int g = blockIdx.z, hb = hb0 + g;
    int i0 = blockIdx.y << 6, j0 = blockIdx.x << 6;
    int t = threadIdx.x;
    const float* qbase = qh + ((size_t)hb * NN + i0) * DH;
    const float* kbase = kh + ((size_t)hb * NN + j0) * DH;
    for (int e = t; e < 64 * DH; e += 256) {
        int r = e / DH, d = e - r * DH;
        Qt[d * DH + r] = qbase[e];
        Kt[d * DH + r] = kbase[e];
    }
    __syncthreads();
    int tx = t & 15, ty = t >> 4;
    float acc[4][4] = {};
    #pragma unroll 4
    for (int k = 0; k < DH; k++) {
        float4 a4 = *(const float4*)&Qt[k * DH + (ty << 2)];
        float4 b4 = *(const float4*)&Kt[k * DH + (tx << 2)];
        float ar_[4] = {a4.x, a4.y, a4.z, a4.w};
        float br_[4] = {b4.x, b4.y, b4.z, b4.w};
        #pragma unroll
        for (int r = 0; r < 4; r++)
            #pragma unroll
            for (int c = 0; c < 4; c++)
                acc[r][c] = fmaf(ar_[r], br_[c], acc[r][c]);
    }
    #pragma unroll
    for (int r = 0; r < 4; r++) {
        float4 o;
        o.x = acc[r][0]; o.y = acc[r][1]; o.z = acc[r][2]; o.w = acc[r][3];
        *(float4*)(simBuf + ((size_t)g * NN + i0 + (ty << 2) + r) * NN + j0 + (tx << 2)) = o;
    }
}

// ---------------- exact top-k threshold: wave-per-row bisection ----------------
__device__ __forceinline__ unsigned fmap(float f) {
    unsigned u = __float_as_uint(f);
    return (u & 0x80000000u) ? ~u : (u | 0x80000000u);
}
__device__ __forceinline__ float funmap(unsigned u) {
    return __uint_as_float((u & 0x80000000u) ? (u & 0x7fffffffu) : ~u);
}

__device__ __forceinline__ int waveCountGE(const unsigned* u, unsigned piv) {
    int c = 0;
    #pragma unroll
    for (int j = 0; j < 32; j++) c += (u[j] >= piv) ? 1 : 0;
    #pragma unroll
    for (int o = 32; o > 0; o >>= 1) c += __shfl_down(c, o);
    return __shfl(c, 0);
}

__global__ __launch_bounds__(256) void topk_kernel(const float* __restrict__ sim, int hb0,
                                                   const int* __restrict__ topt,
                                                   int* __restrict__ keptIdx,
                                                   float* __restrict__ keptVal,
                                                   int* __restrict__ keptCnt)
{
    int rid = (blockIdx.x << 2) + (threadIdx.x >> 6);
    int lane = threadIdx.x & 63;
    int g = rid >> 11, i = rid & (NN - 1);
    int hb = hb0 + g;
    const float* row = sim + ((size_t)rid << 11);
    int k = topt[0];

    unsigned u[32];
    #pragma unroll
    for (int c = 0; c < 32; c++) u[c] = fmap(row[(c << 6) + lane]);

    unsigned lo = 0u, hi = 0xFFFFFFFFu;
    while (lo < hi) {
        unsigned mid = lo + ((hi - lo) >> 1) + 1u;
        int cnt = waveCountGE(u, mid);
        if (cnt >= k) lo = mid; else hi = mid - 1u;
    }
    unsigned kth = lo;
    int total = waveCountGE(u, kth);

    size_t base = ((size_t)hb * NN + i) * CAP;
    int pbase = 0;
    #pragma unroll
    for (int c = 0; c < 32; c++) {
        bool p = (u[c] >= kth);
        unsigned long long m = __ballot(p);
        if (p) {
            int pos = pbase + (int)__popcll(m & ((1ull << lane) - 1ull));
            if (pos < CAP) {
                keptIdx[base + pos] = (c << 6) + lane;
                keptVal[base + pos] = funmap(u[c]);
            }
        }
        pbase += (int)__popcll(m);
    }
    if (lane == 0) keptCnt[hb * NN + i] = (total < CAP) ? total : CAP;
}

// ---------------- column partition function Z_j ----------------
__global__ __launch_bounds__(256) void colz_kernel(const int* __restrict__ keptIdx,
                                                   const float* __restrict__ keptVal,
                                                   const int* __restrict__ keptCnt,
                                                   float* __restrict__ colZ)
{
    unsigned gid = blockIdx.x * 256u + threadIdx.x;
    if (gid >= (unsigned)NHB * NN * CAP) return;
    int p = gid % CAP;
    unsigned rid = gid / CAP;
    if (p < keptCnt[rid]) {
        int hb = rid >> 11;
        atomicAdd(&colZ[(hb << 11) + keptIdx[(size_t)rid * CAP + p]],
                  expf(keptVal[(size_t)rid * CAP + p]));
    }
}

// ---------------- per-head stats (grid NHB x 8, atomic accumulate) ----------------
__global__ void stats_kernel(const float* __restrict__ colZ, const float* __restrict__ vh,
                             int* __restrict__ nE, float* __restrict__ vsumE,
                             float* __restrict__ vsumAll)
{
    int hb = blockIdx.x, jb = blockIdx.y;
    int t = threadIdx.x;   // 272 = 4*68
    int ty = t / DH, d = t - ty * DH;
    float aAll = 0.f, aE = 0.f;
    int cE = 0;
    for (int j = (jb << 8) + ty; j < (jb << 8) + 256; j += 4) {
        float z = colZ[(hb << 11) + j];
        float vv = vh[((size_t)(hb << 11) + j) * DH + d];
        aAll += vv;
        if (z == 0.0f) { aE += vv; cE++; }
    }
    __shared__ float sAll[4][DH], sE[4][DH];
    __shared__ int sC[4];
    sAll[ty][d] = aAll;
    sE[ty][d] = aE;
    if (d == 0) sC[ty] = cE;
    __syncthreads();
    if (ty == 0) {
        atomicAdd(&vsumAll[hb * DH + d], sAll[0][d] + sAll[1][d] + sAll[2][d] + sAll[3][d]);
        atomicAdd(&vsumE[hb * DH + d],   sE[0][d] + sE[1][d] + sE[2][d] + sE[3][d]);
        if (d == 0) atomicAdd(&nE[hb], sC[0] + sC[1] + sC[2] + sC[3]);
    }
}

// ---------------- sparse PV + renorm; emits outc hi/lo bf16 (c<1024) and d_out PE cols ----------------
__global__ __launch_bounds__(128) void pv_kernel(const int* __restrict__ keptIdx,
                                                 const float* __restrict__ keptVal,
                                                 const int* __restrict__ keptCnt,
                                                 const float* __restrict__ colZ,
                                                 const float* __restrict__ vh,
                                                 const int* __restrict__ nE,
                                                 const float* __restrict__ vsumE,
                                                 const float* __restrict__ vsumAll,
                                                 ushort* __restrict__ outcH,
                                                 ushort* __restrict__ outcL,
                                                 float* __restrict__ dout)
{
    int bid = blockIdx.x;
    int hb = bid >> 11, i = bid & (NN - 1);
    int t = threadIdx.x;
    __shared__ float w[CAP];
    __shared__ int jj[CAP];
    __shared__ float rowsum_s;
    int cnt = keptCnt[bid];
    size_t base = (size_t)bid * CAP;
    if (t < cnt) {
        int j = keptIdx[base + t];
        jj[t] = j;
        w[t] = expf(keptVal[base + t]) / colZ[(hb << 11) + j];
    }
    __syncthreads();
    if (t == 0) {
        float s = 0.f;
        for (int p = 0; p < cnt; p++) s += w[p];
        rowsum_s = s + (float)nE[hb] * (1.0f / NN) + (float)NN * 1e-6f;
    }
    __syncthreads();
    if (t < DH) {
        float acc = 1e-6f * vsumAll[hb * DH + t] + (1.0f / NN) * vsumE[hb * DH + t];
        const float* vbase = vh + ((size_t)(hb << 11)) * DH;
        for (int p = 0; p < cnt; p++)
            acc = fmaf(w[p], vbase[(size_t)jj[p] * DH + t], acc);
        float val = acc / rowsum_s;
        int hh = hb & (NHEAD - 1), b0 = hb >> 4;
        int row = (b0 << 11) + i;
        int c = hh * DH + t;
        if (c < D) {
            ushort h, l;
            bf16split(val, h, l);
            outcH[(size_t)row * D + c] = h;
            outcL[(size_t)row * D + c] = l;
        } else {
            dout[(size_t)row * (D + PED) + c] = val;
        }
    }
}

// ---------------- launch ----------------
extern "C" void kernel_launch(void* const* d_in, const int* in_sizes, int n_in,
                              void* d_out, int out_size, void* d_ws, size_t ws_size,
                              hipStream_t stream)
{
    (void)in_sizes; (void)n_in; (void)out_size;
    const float* sink = (const float*)d_in[0];
    const float* gno  = (const float*)d_in[1];
    const float* bno  = (const float*)d_in[2];
    const float* Wq   = (const float*)d_in[3];
    const float* bq   = (const float*)d_in[4];
    const float* Wkv  = (const float*)d_in[5];
    const float* bkv  = (const float*)d_in[6];
    const float* Wout = (const float*)d_in[7];
    const float* bout = (const float*)d_in[8];
    const int*   topt = (const int*)d_in[9];
    float* out = (float*)d_out;

    char* ws = (char*)d_ws;
    size_t off = 0;
    float* qkv = (float*)(ws + off); off += (size_t)TT * 3072 * 4;           // 48 MB (dead after repack -> simBuf fallback)
    float* qh      = (float*)(ws + off); off += (size_t)NHB * NN * DH * 4;
    float* kh      = (float*)(ws + off); off += (size_t)NHB * NN * DH * 4;
    float* vh      = (float*)(ws + off); off += (size_t)NHB * NN * DH * 4;
    int*   keptIdx = (int*)  (ws + off); off += (size_t)NHB * NN * CAP * 4;
    float* keptVal = (float*)(ws + off); off += (size_t)NHB * NN * CAP * 4;
    int*   keptCnt = (int*)  (ws + off); off += (size_t)NHB * NN * 4;
    float* colZ    = (float*)(ws + off); off += (size_t)NHB * NN * 4;
    ushort* featH  = (ushort*)(ws + off); off += (size_t)TT * D * 2;
    ushort* featL  = (ushort*)(ws + off); off += (size_t)TT * D * 2;
    ushort* WTH    = (ushort*)(ws + off); off += (size_t)3072 * 1024 * 2;
    ushort* WTL    = (ushort*)(ws + off); off += (size_t)3072 * 1024 * 2;
    ushort* WoutTH = (ushort*)(ws + off); off += (size_t)D * D * 2;
    ushort* WoutTL = (ushort*)(ws + off); off += (size_t)D * D * 2;
    ushort* outcH  = (ushort*)(ws + off); off += (size_t)TT * D * 2;
    ushort* outcL  = (ushort*)(ws + off); off += (size_t)TT * D * 2;
    char*  statsZ  = (char*)(ws + off);
    int*   nE      = (int*)  (ws + off); off += 256;
    float* vsumE   = (float*)(ws + off); off += (size_t)NHB * DH * 4 + 192;
    float* vsumAll = (float*)(ws + off); off += (size_t)NHB * DH * 4 + 192;
    size_t statsBytes = (size_t)((char*)(ws + off) - statsZ);
    off = (off + 255) & ~(size_t)255;

    size_t simBytesPerHead = (size_t)NN * NN * 4;
    size_t tail = (ws_size > off) ? (ws_size - off) : 0;
    int Gtail = (int)(tail / simBytesPerHead);
    float* simBuf;
    int G;
    if (Gtail > 3) {
        simBuf = (float*)(ws + off);
        G = (Gtail < NHB) ? Gtail : NHB;
    } else {
        simBuf = qkv;   // 48 MB region, dead after repack
        G = 3;
    }

    ln_kernel<<<TT, 256, 0, stream>>>(sink, gno, bno, featH, featL);
    tsplit<<<dim3(D / 64, D / 64), 256, 0, stream>>>(Wq, D, WTH, WTL);
    tsplit<<<dim3(2 * D / 64, D / 64), 256, 0, stream>>>(Wkv, 2 * D, WTH + (size_t)1024 * 1024, WTL + (size_t)1024 * 1024);
    tsplit<<<dim3(D / 64, D / 64), 256, 0, stream>>>(Wout, D, WoutTH, WoutTL);
    gemm_mfma<<<dim3(3072 / 128, TT / 128), 256, 0, stream>>>(featH, featL, WTH, WTL, bq, bkv, 1024, qkv, 3072);
    repack_kernel<<<((unsigned)NHB * NN * DH + 255) / 256, 256, 0, stream>>>(qkv, sink, qh, kh, vh);
    hipMemsetAsync(colZ, 0, (size_t)NHB * NN * 4, stream);
    hipMemsetAsync(statsZ, 0, statsBytes, stream);

    for (int hb0 = 0; hb0 < NHB; hb0 += G) {
        int gc = (NHB - hb0 < G) ? (NHB - hb0) : G;
        sim_kernel<<<dim3(NN / 64, NN / 64, gc), 256, 0, stream>>>(qh, kh, simBuf, hb0);
        topk_kernel<<<gc * 512, 256, 0, stream>>>(simBuf, hb0, topt, keptIdx, keptVal, keptCnt);
    }

    colz_kernel<<<((unsigned)NHB * NN * CAP + 255) / 256, 256, 0, stream>>>(keptIdx, keptVal, keptCnt, colZ);
    stats_kernel<<<dim3(NHB, 8), 4 * DH, 0, stream>>>(colZ, vh, nE, vsumE, vsumAll);
    pv_kernel<<<NHB * NN, 128, 0, stream>>>(keptIdx, keptVal, keptCnt, colZ, vh, nE, vsumE, vsumAll, outcH, outcL, out);
    gemm_mfma<<<dim3(D / 128, TT / 128), 256, 0, stream>>>(outcH, outcL, WoutTH, WoutTL, bout, bout, 1024, out, D + PED);
}

// Round 11
// 1183.939 us; speedup vs baseline: 1.4909x; 1.1372x over previous
//
#include <hip/hip_runtime.h>
#include <hip/hip_bf16.h>

#define D     1024
#define PED   64
#define NHEAD 16
#define NB    2
#define NN    2048
#define NHB   32      // NB*NHEAD
#define DH    68      // (D+PED)/NHEAD
#define TT    4096    // NB*NN
#define CAP   68      // kept-entry capacity per row (64 + tie slack)

typedef __attribute__((ext_vector_type(8))) short short8v;
typedef __attribute__((ext_vector_type(4))) float f32x4;

__device__ __forceinline__ void gload16(const void* g, void* l) {
    __builtin_amdgcn_global_load_lds((const __attribute__((address_space(1))) void*)g,
                                     (__attribute__((address_space(3))) void*)l, 16, 0, 0);
}

__device__ __forceinline__ void bf16split(float v, ushort& h, ushort& l) {
    __hip_bfloat16 hb = __float2bfloat16(v);
    float r = v - __bfloat162float(hb);
    __hip_bfloat16 lb = __float2bfloat16(r);
    h = *(ushort*)&hb; l = *(ushort*)&lb;
}

// ---------------- LayerNorm -> bf16 hi/lo directly ----------------
__global__ __launch_bounds__(256) void ln_kernel(const float* __restrict__ sink,
                                                 const float* __restrict__ gw,
                                                 const float* __restrict__ bw,
                                                 ushort* __restrict__ featH,
                                                 ushort* __restrict__ featL)
{
    int row = blockIdx.x, t = threadIdx.x;
    const float* x = sink + (size_t)row * (D + PED);
    float4 v = *(const float4*)(x + (t << 2));
    float s = v.x + v.y + v.z + v.w;
    __shared__ float red[4];
    __shared__ float mu_s, rstd_s;
    for (int o = 32; o > 0; o >>= 1) s += __shfl_down(s, o);
    if ((t & 63) == 0) red[t >> 6] = s;
    __syncthreads();
    if (t == 0) mu_s = (red[0] + red[1] + red[2] + red[3]) * (1.0f / D);
    __syncthreads();
    float mu = mu_s;
    float dx = v.x - mu, dy = v.y - mu, dz = v.z - mu, dw = v.w - mu;
    float s2 = dx*dx + dy*dy + dz*dz + dw*dw;
    for (int o = 32; o > 0; o >>= 1) s2 += __shfl_down(s2, o);
    if ((t & 63) == 0) red[t >> 6] = s2;
    __syncthreads();
    if (t == 0) rstd_s = rsqrtf((red[0] + red[1] + red[2] + red[3]) * (1.0f / D) + 1e-6f);
    __syncthreads();
    float rstd = rstd_s;
    float4 gv = *(const float4*)(gw + (t << 2));
    float4 bv = *(const float4*)(bw + (t << 2));
    float o4[4];
    o4[0] = dx * rstd * gv.x + bv.x;
    o4[1] = dy * rstd * gv.y + bv.y;
    o4[2] = dz * rstd * gv.z + bv.z;
    o4[3] = dw * rstd * gv.w + bv.w;
    ushort4 H, L;
    bf16split(o4[0], H.x, L.x);
    bf16split(o4[1], H.y, L.y);
    bf16split(o4[2], H.z, L.z);
    bf16split(o4[3], H.w, L.w);
    *(ushort4*)(featH + (size_t)row * D + (t << 2)) = H;
    *(ushort4*)(featL + (size_t)row * D + (t << 2)) = L;
}

// ---------------- transpose + split: W[K=1024][N_] fp32 -> T{H,L}[N_][1024] bf16 ----------------
__global__ __launch_bounds__(256) void tsplit(const float* __restrict__ W, int N_,
                                              ushort* __restrict__ TH,
                                              ushort* __restrict__ TL)
{
    __shared__ float tile[64][65];
    int k0 = blockIdx.y << 6, n0 = blockIdx.x << 6;
    int tx = threadIdx.x & 63, ty4 = threadIdx.x >> 6;
    for (int r = ty4; r < 64; r += 4)
        tile[r][tx] = W[(size_t)(k0 + r) * N_ + n0 + tx];
    __syncthreads();
    for (int r = ty4; r < 64; r += 4) {
        ushort h, l;
        bf16split(tile[tx][r], h, l);
        TH[(size_t)(n0 + r) * 1024 + k0 + tx] = h;
        TL[(size_t)(n0 + r) * 1024 + k0 + tx] = l;
    }
}

// ---------------- bf16x3-split MFMA GEMM, LDS-staged, 128x128 tile, dbuf 2-phase ----------------
__global__ __launch_bounds__(256) void gemm_mfma(const ushort* __restrict__ AHg,
                                                 const ushort* __restrict__ ALg,
                                                 const ushort* __restrict__ BHg,
                                                 const ushort* __restrict__ BLg,
                                                 const float* __restrict__ biasA,
                                                 const float* __restrict__ biasB,
                                                 int bSplit,
                                                 float* __restrict__ C, int ldc)
{
    __shared__ ushort ldsAH[2][4096];   // [buf][128 rows * 32 k]
    __shared__ ushort ldsAL[2][4096];
    __shared__ ushort ldsBH[2][4096];
    __shared__ ushort ldsBL[2][4096];

    int t = threadIdx.x;
    int nwg = gridDim.x * gridDim.y;
    int bid = blockIdx.y * gridDim.x + blockIdx.x;
    int qq = nwg >> 3;
    int swz = (bid & 7) * qq + (bid >> 3);
    int nb = swz % gridDim.x, mb = swz / gridDim.x;
    int m0 = mb << 7, n0 = nb << 7;

    int w = t >> 6, lane = t & 63;
    int wm = w >> 1, wn = w & 1;
    int lr = lane & 15, lg = lane >> 4;

    f32x4 acc[4][4] = {};

#define STAGE(buf, kt) do {                                                          \
    int k0_ = (kt) << 5;                                                             \
    _Pragma("unroll")                                                                \
    for (int c2 = 0; c2 < 2; c2++) {                                                 \
        int idx = t + (c2 << 8);                                                     \
        int row_ = idx >> 2, kp_ = idx & 3;                                          \
        size_t ga = (size_t)(m0 + row_) * 1024 + k0_ + (kp_ << 3);                   \
        size_t gb = (size_t)(n0 + row_) * 1024 + k0_ + (kp_ << 3);                   \
        gload16(AHg + ga, &ldsAH[buf][idx << 3]);                                    \
        gload16(ALg + ga, &ldsAL[buf][idx << 3]);                                    \
        gload16(BHg + gb, &ldsBH[buf][idx << 3]);                                    \
        gload16(BLg + gb, &ldsBL[buf][idx << 3]);                                    \
    }                                                                                \
} while (0)

    STAGE(0, 0);
    __syncthreads();
    #pragma unroll 2
    for (int kt = 0; kt < 32; kt++) {
        int cur = kt & 1;
        if (kt < 31) STAGE(cur ^ 1, kt + 1);
        short8v ah[4], al[4];
        #pragma unroll
        for (int mf = 0; mf < 4; mf++) {
            int idx = ((wm << 6) + (mf << 4) + lr) * 32 + (lg << 3);
            ah[mf] = *(const short8v*)&ldsAH[cur][idx];
            al[mf] = *(const short8v*)&ldsAL[cur][idx];
        }
        #pragma unroll
        for (int nf = 0; nf < 4; nf++) {
            int idx = ((wn << 6) + (nf << 4) + lr) * 32 + (lg << 3);
            short8v bh = *(const short8v*)&ldsBH[cur][idx];
            short8v bl = *(const short8v*)&ldsBL[cur][idx];
            #pragma unroll
            for (int mf = 0; mf < 4; mf++) {
                acc[mf][nf] = __builtin_amdgcn_mfma_f32_16x16x32_bf16(ah[mf], bh, acc[mf][nf], 0, 0, 0);
                acc[mf][nf] = __builtin_amdgcn_mfma_f32_16x16x32_bf16(ah[mf], bl, acc[mf][nf], 0, 0, 0);
                acc[mf][nf] = __builtin_amdgcn_mfma_f32_16x16x32_bf16(al[mf], bh, acc[mf][nf], 0, 0, 0);
            }
        }
        __syncthreads();
    }
#undef STAGE

    #pragma unroll
    for (int nf = 0; nf < 4; nf++) {
        int col = n0 + (wn << 6) + (nf << 4) + lr;
        float bv = (col < bSplit) ? biasA[col] : biasB[col - bSplit];
        #pragma unroll
        for (int mf = 0; mf < 4; mf++) {
            int rowb = m0 + (wm << 6) + (mf << 4) + (lg << 2);
            #pragma unroll
            for (int j = 0; j < 4; j++)
                C[(size_t)(rowb + j) * ldc + col] = acc[mf][nf][j] + bv;
        }
    }
}

// ---------------- repack qkv -> per-head q/k/v (scale 0.125 folded into q) ----------------
__global__ __launch_bounds__(256) void repack_kernel(const float* __restrict__ qkv,
                                                     const float* __restrict__ sink,
                                                     float* __restrict__ qh,
                                                     float* __restrict__ kh,
                                                     float* __restrict__ vh)
{
    unsigned gid = blockIdx.x * 256u + threadIdx.x;
    if (gid >= (unsigned)NHB * NN * DH) return;
    int d = gid % DH;
    unsigned r2 = gid / DH;
    int i = r2 & (NN - 1);
    int hb = r2 >> 11;
    int hh = hb & (NHEAD - 1), b0 = hb >> 4;
    int row = (b0 << 11) + i;
    int c = hh * DH + d;
    float qv, kvv, vv;
    if (c < D) {
        const float* base = qkv + (size_t)row * 3072;
        qv  = base[c];
        kvv = base[1024 + c];
        vv  = base[2048 + c];
    } else {
        float pe = sink[(size_t)row * (D + PED) + c];
        qv = pe; kvv = pe; vv = pe;
    }
    qh[gid] = 0.125f * qv;
    kh[gid] = kvv;
    vh[gid] = vv;
}

// ---------------- sim = Qh · Khᵀ per head (64x64 tiles) ----------------
__global__ __launch_bounds__(256) void sim_kernel(const float* __restrict__ qh,
                                                  const float* __restrict__ kh,
                                                  float* __restrict__ simBuf, int hb0)
{
    __shared__ float Qt[DH * DH];
    __shared__ float Kt[DH * DH];
    int g = blockIdx.z, hb = hb0 + g;
    int i0 = blockIdx.y << 6, j0 = blockIdx.x << 6;
    int t = threadIdx.x;
    const float* qbase = qh + ((size_t)hb * NN + i0) * DH;
    const float* kbase = kh + ((size_t)hb * NN + j0) * DH;
    for (int e = t; e < 64 * DH; e += 256) {
        int r = e / DH, d = e - r * DH;
        Qt[d * DH + r] = qbase[e];
        Kt[d * DH + r] = kbase[e];
    }
    __syncthreads();
    int tx = t & 15, ty = t >> 4;
    float acc[4][4] = {};
    #pragma unroll 4
    for (int k = 0; k < DH; k++) {
        float4 a4 = *(const float4*)&Qt[k * DH + (ty << 2)];
        float4 b4 = *(const float4*)&Kt[k * DH + (tx << 2)];
        float ar_[4] = {a4.x, a4.y, a4.z, a4.w};
        float br_[4] = {b4.x, b4.y, b4.z, b4.w};
        #pragma unroll
        for (int r = 0; r < 4; r++)
            #pragma unroll
            for (int c = 0; c < 4; c++)
                acc[r][c] = fmaf(ar_[r], br_[c], acc[r][c]);
    }
    #pragma unroll
    for (int r = 0; r < 4; r++) {
        float4 o;
        o.x = acc[r][0]; o.y = acc[r][1]; o.z = acc[r][2]; o.w = acc[r][3];
        *(float4*)(simBuf + ((size_t)g * NN + i0 + (ty << 2) + r) * NN + j0 + (tx << 2)) = o;
    }
}

// ---------------- exact top-k threshold: wave-per-row bisection ----------------
__device__ __forceinline__ unsigned fmap(float f) {
    unsigned u = __float_as_uint(f);
    return (u & 0x80000000u) ? ~u : (u | 0x80000000u);
}
__device__ __forceinline__ float funmap(unsigned u) {
    return __uint_as_float((u & 0x80000000u) ? (u & 0x7fffffffu) : ~u);
}

__device__ __forceinline__ int waveCountGE(const unsigned* u, unsigned piv) {
    int c = 0;
    #pragma unroll
    for (int j = 0; j < 32; j++) c += (u[j] >= piv) ? 1 : 0;
    #pragma unroll
    for (int o = 32; o > 0; o >>= 1) c += __shfl_down(c, o);
    return __shfl(c, 0);
}

__global__ __launch_bounds__(256) void topk_kernel(const float* __restrict__ sim, int hb0,
                                                   const int* __restrict__ topt,
                                                   int* __restrict__ keptIdx,
                                                   float* __restrict__ keptVal,
                                                   int* __restrict__ keptCnt)
{
    int rid = (blockIdx.x << 2) + (threadIdx.x >> 6);
    int lane = threadIdx.x & 63;
    int g = rid >> 11, i = rid & (NN - 1);
    int hb = hb0 + g;
    const float* row = sim + ((size_t)rid << 11);
    int k = topt[0];

    unsigned u[32];
    #pragma unroll
    for (int c = 0; c < 32; c++) u[c] = fmap(row[(c << 6) + lane]);

    unsigned lo = 0u, hi = 0xFFFFFFFFu;
    while (lo < hi) {
        unsigned mid = lo + ((hi - lo) >> 1) + 1u;
        int cnt = waveCountGE(u, mid);
        if (cnt >= k) lo = mid; else hi = mid - 1u;
    }
    unsigned kth = lo;
    int total = waveCountGE(u, kth);

    size_t base = ((size_t)hb * NN + i) * CAP;
    int pbase = 0;
    #pragma unroll
    for (int c = 0; c < 32; c++) {
        bool p = (u[c] >= kth);
        unsigned long long m = __ballot(p);
        if (p) {
            int pos = pbase + (int)__popcll(m & ((1ull << lane) - 1ull));
            if (pos < CAP) {
                keptIdx[base + pos] = (c << 6) + lane;
                keptVal[base + pos] = funmap(u[c]);
            }
        }
        pbase += (int)__popcll(m);
    }
    if (lane == 0) keptCnt[hb * NN + i] = (total < CAP) ? total : CAP;
}

// ---------------- column partition function Z_j — LDS-privatized per (head, 256-row block) ----------------
__global__ __launch_bounds__(256) void colz_kernel(const int* __restrict__ keptIdx,
                                                   const float* __restrict__ keptVal,
                                                   const int* __restrict__ keptCnt,
                                                   float* __restrict__ colZ)
{
    __shared__ float zloc[NN];
    int hb = blockIdx.x;
    int i0 = blockIdx.y << 8;            // 256-row slice of this head
    int t = threadIdx.x;
    int wave = t >> 6, lane = t & 63;
    for (int j = t; j < NN; j += 256) zloc[j] = 0.f;
    __syncthreads();
    for (int r = wave; r < 256; r += 4) {
        int rid = (hb << 11) + i0 + r;
        int cnt = keptCnt[rid];
        size_t base = (size_t)rid * CAP;
        if (lane < cnt)
            atomicAdd(&zloc[keptIdx[base + lane]], expf(keptVal[base + lane]));
        if (lane + 64 < cnt)
            atomicAdd(&zloc[keptIdx[base + lane + 64]], expf(keptVal[base + lane + 64]));
    }
    __syncthreads();
    for (int j = t; j < NN; j += 256) {
        float z = zloc[j];
        if (z != 0.0f) atomicAdd(&colZ[(hb << 11) + j], z);
    }
}

// ---------------- per-head stats (grid NHB x 8, atomic accumulate) ----------------
__global__ void stats_kernel(const float* __restrict__ colZ, const float* __restrict__ vh,
                             int* __restrict__ nE, float* __restrict__ vsumE,
                             float* __restrict__ vsumAll)
{
    int hb = blockIdx.x, jb = blockIdx.y;
    int t = threadIdx.x;   // 272 = 4*68
    int ty = t / DH, d = t - ty * DH;
    float aAll = 0.f, aE = 0.f;
    int cE = 0;
    for (int j = (jb << 8) + ty; j < (jb << 8) + 256; j += 4) {
        float z = colZ[(hb << 11) + j];
        float vv = vh[((size_t)(hb << 11) + j) * DH + d];
        aAll += vv;
        if (z == 0.0f) { aE += vv; cE++; }
    }
    __shared__ float sAll[4][DH], sE[4][DH];
    __shared__ int sC[4];
    sAll[ty][d] = aAll;
    sE[ty][d] = aE;
    if (d == 0) sC[ty] = cE;
    __syncthreads();
    if (ty == 0) {
        atomicAdd(&vsumAll[hb * DH + d], sAll[0][d] + sAll[1][d] + sAll[2][d] + sAll[3][d]);
        atomicAdd(&vsumE[hb * DH + d],   sE[0][d] + sE[1][d] + sE[2][d] + sE[3][d]);
        if (d == 0) atomicAdd(&nE[hb], sC[0] + sC[1] + sC[2] + sC[3]);
    }
}

// ---------------- sparse PV + renorm; emits outc hi/lo bf16 (c<1024) and d_out PE cols ----------------
__global__ __launch_bounds__(128) void pv_kernel(const int* __restrict__ keptIdx,
                                                 const float* __restrict__ keptVal,
                                                 const int* __restrict__ keptCnt,
                                                 const float* __restrict__ colZ,
                                                 const float* __restrict__ vh,
                                                 const int* __restrict__ nE,
                                                 const float* __restrict__ vsumE,
                                                 const float* __restrict__ vsumAll,
                                                 ushort* __restrict__ outcH,
                                                 ushort* __restrict__ outcL,
                                                 float* __restrict__ dout)
{
    int bid = blockIdx.x;
    int hb = bid >> 11, i = bid & (NN - 1);
    int t = threadIdx.x;
    __shared__ float w[CAP];
    __shared__ int jj[CAP];
    __shared__ float rowsum_s;
    int cnt = keptCnt[bid];
    size_t base = (size_t)bid * CAP;
    if (t < cnt) {
        int j = keptIdx[base + t];
        jj[t] = j;
        w[t] = expf(keptVal[base + t]) / colZ[(hb << 11) + j];
    }
    __syncthreads();
    if (t == 0) {
        float s = 0.f;
        for (int p = 0; p < cnt; p++) s += w[p];
        rowsum_s = s + (float)nE[hb] * (1.0f / NN) + (float)NN * 1e-6f;
    }
    __syncthreads();
    if (t < DH) {
        float acc = 1e-6f * vsumAll[hb * DH + t] + (1.0f / NN) * vsumE[hb * DH + t];
        const float* vbase = vh + ((size_t)(hb << 11)) * DH;
        for (int p = 0; p < cnt; p++)
            acc = fmaf(w[p], vbase[(size_t)jj[p] * DH + t], acc);
        float val = acc / rowsum_s;
        int hh = hb & (NHEAD - 1), b0 = hb >> 4;
        int row = (b0 << 11) + i;
        int c = hh * DH + t;
        if (c < D) {
            ushort h, l;
            bf16split(val, h, l);
            outcH[(size_t)row * D + c] = h;
            outcL[(size_t)row * D + c] = l;
        } else {
            dout[(size_t)row * (D + PED) + c] = val;
        }
    }
}

// ---------------- launch ----------------
extern "C" void kernel_launch(void* const* d_in, const int* in_sizes, int n_in,
                              void* d_out, int out_size, void* d_ws, size_t ws_size,
                              hipStream_t stream)
{
    (void)in_sizes; (void)n_in; (void)out_size;
    const float* sink = (const float*)d_in[0];
    const float* gno  = (const float*)d_in[1];
    const float* bno  = (const float*)d_in[2];
    const float* Wq   = (const float*)d_in[3];
    const float* bq   = (const float*)d_in[4];
    const float* Wkv  = (const float*)d_in[5];
    const float* bkv  = (const float*)d_in[6];
    const float* Wout = (const float*)d_in[7];
    const float* bout = (const float*)d_in[8];
    const int*   topt = (const int*)d_in[9];
    float* out = (float*)d_out;

    char* ws = (char*)d_ws;
    size_t off = 0;
    float* qkv = (float*)(ws + off); off += (size_t)TT * 3072 * 4;           // 48 MB (dead after repack -> simBuf fallback)
    float* qh      = (float*)(ws + off); off += (size_t)NHB * NN * DH * 4;
    float* kh      = (float*)(ws + off); off += (size_t)NHB * NN * DH * 4;
    float* vh      = (float*)(ws + off); off += (size_t)NHB * NN * DH * 4;
    int*   keptIdx = (int*)  (ws + off); off += (size_t)NHB * NN * CAP * 4;
    float* keptVal = (float*)(ws + off); off += (size_t)NHB * NN * CAP * 4;
    int*   keptCnt = (int*)  (ws + off); off += (size_t)NHB * NN * 4;
    float* colZ    = (float*)(ws + off); off += (size_t)NHB * NN * 4;
    ushort* featH  = (ushort*)(ws + off); off += (size_t)TT * D * 2;
    ushort* featL  = (ushort*)(ws + off); off += (size_t)TT * D * 2;
    ushort* WTH    = (ushort*)(ws + off); off += (size_t)3072 * 1024 * 2;
    ushort* WTL    = (ushort*)(ws + off); off += (size_t)3072 * 1024 * 2;
    ushort* WoutTH = (ushort*)(ws + off); off += (size_t)D * D * 2;
    ushort* WoutTL = (ushort*)(ws + off); off += (size_t)D * D * 2;
    ushort* outcH  = (ushort*)(ws + off); off += (size_t)TT * D * 2;
    ushort* outcL  = (ushort*)(ws + off); off += (size_t)TT * D * 2;
    char*  statsZ  = (char*)(ws + off);
    int*   nE      = (int*)  (ws + off); off += 256;
    float* vsumE   = (float*)(ws + off); off += (size_t)NHB * DH * 4 + 192;
    float* vsumAll = (float*)(ws + off); off += (size_t)NHB * DH * 4 + 192;
    size_t statsBytes = (size_t)((char*)(ws + off) - statsZ);
    off = (off + 255) & ~(size_t)255;

    size_t simBytesPerHead = (size_t)NN * NN * 4;
    size_t tail = (ws_size > off) ? (ws_size - off) : 0;
    int Gtail = (int)(tail / simBytesPerHead);
    float* simBuf;
    int G;
    if (Gtail > 3) {
        simBuf = (float*)(ws + off);
        G = (Gtail < NHB) ? Gtail : NHB;
    } else {
        simBuf = qkv;   // 48 MB region, dead after repack
        G = 3;
    }

    ln_kernel<<<TT, 256, 0, stream>>>(sink, gno, bno, featH, featL);
    tsplit<<<dim3(D / 64, D / 64), 256, 0, stream>>>(Wq, D, WTH, WTL);
    tsplit<<<dim3(2 * D / 64, D / 64), 256, 0, stream>>>(Wkv, 2 * D, WTH + (size_t)1024 * 1024, WTL + (size_t)1024 * 1024);
    tsplit<<<dim3(D / 64, D / 64), 256, 0, stream>>>(Wout, D, WoutTH, WoutTL);
    gemm_mfma<<<dim3(3072 / 128, TT / 128), 256, 0, stream>>>(featH, featL, WTH, WTL, bq, bkv, 1024, qkv, 3072);
    repack_kernel<<<((unsigned)NHB * NN * DH + 255) / 256, 256, 0, stream>>>(qkv, sink, qh, kh, vh);
    hipMemsetAsync(colZ, 0, (size_t)NHB * NN * 4, stream);
    hipMemsetAsync(statsZ, 0, statsBytes, stream);

    for (int hb0 = 0; hb0 < NHB; hb0 += G) {
        int gc = (NHB - hb0 < G) ? (NHB - hb0) : G;
        sim_kernel<<<dim3(NN / 64, NN / 64, gc), 256, 0, stream>>>(qh, kh, simBuf, hb0);
        topk_kernel<<<gc * 512, 256, 0, stream>>>(simBuf, hb0, topt, keptIdx, keptVal, keptCnt);
    }

    colz_kernel<<<dim3(NHB, 8), 256, 0, stream>>>(keptIdx, keptVal, keptCnt, colZ);
    stats_kernel<<<dim3(NHB, 8), 4 * DH, 0, stream>>>(colZ, vh, nE, vsumE, vsumAll);
    pv_kernel<<<NHB * NN, 128, 0, stream>>>(keptIdx, keptVal, keptCnt, colZ, vh, nE, vsumE, vsumAll, outcH, outcL, out);
    gemm_mfma<<<dim3(D / 128, TT / 128), 256, 0, stream>>>(outcH, outcL, WoutTH, WoutTL, bout, bout, 1024, out, D + PED);
}